// Round 9
// baseline (421.504 us; speedup 1.0000x reference)
//
#include <hip/hip_runtime.h>
#include <math.h>

#define BH 32
#define L  2048
#define D  64
#define SK 40
#define NT 40
#define NC 16          // key chunks for split-K attention
#define CK 128         // keys per chunk (NC*CK == L)
#define SP 129         // padded LDS stride for S (kills 4-way bank conflict)
#define SCALE 0.125f

// ---- workspace layout (bytes) ----
#define WS_M      0                  // float[BH*L]            = 256 KB
#define WS_MTOP   262144             // int[BH*NT]             = 5 KB
#define WS_VP     267264             // float[1024*64]         = 256 KB
#define WS_VM     529408             // float[BH*D]            = 8 KB
#define WS_QTOP   537600             // float[BH*NT*D]         = 320 KB
#define WS_OPART  865280             // float[BH*NC*NT*D]      = 5.24 MB
#define WS_MPART  6108160            // float[BH*NC*NT]        = 80 KB
#define WS_LPART  6190080            // float[BH*NC*NT]        = 80 KB
#define WS_CNT    6272000            // uint[64]: cnt1[32] then cnt2[32]

// DPP add: VALU-only cross-lane. dest lane i reads src lane (i-N) mod 16 for row_ror:N.
// 0xB1 = quad_perm xor1, 0x4E = quad_perm xor2, 0x12C = row_ror:12 -> i <- i+4.
template <int CTRL>
__device__ __forceinline__ float dpp_add(float x) {
    int y = __builtin_amdgcn_update_dpp(0, __float_as_int(x), CTRL, 0xF, 0xF, true);
    return x + __int_as_float(y);
}

// =============== Kernel 0: zero the completion counters ===============
__global__ void kInit(unsigned int* __restrict__ cnt) { cnt[threadIdx.x] = 0u; }

// =============== Kernel 1: sampled-scores + V-mean partials + (last block/head)
//                 top-40 radix select + V-mean finalize + Q gather ===============
__global__ __launch_bounds__(512) void kMVTop(const float* __restrict__ Q,
                                              const float* __restrict__ K,
                                              const float* __restrict__ V,
                                              const int* __restrict__ idx,
                                              float* __restrict__ M,
                                              float* __restrict__ Vp,
                                              int* __restrict__ Mtop,
                                              float* __restrict__ Vm,
                                              float* __restrict__ Qtop,
                                              unsigned int* __restrict__ cnt1)
{
    __shared__ int   sidx[64 * SK];    // 10 KB
    __shared__ float red[512];

    int t    = threadIdx.x;
    int b    = blockIdx.x;
    int head = ((b >> 3) & 3) * 8 + (b & 7);   // XCD-swizzled head (32 blocks/head)
    int qc   = b >> 5;                         // 0..31
    int l0   = qc * 64;

    // ---- V-mean partial for rows l0..l0+63 of this head ----
    {
        int d = t & 63, r = t >> 6;            // r = 0..7
        const float* Vb = V + ((size_t)head * L + l0 + r * 8) * D + d;
        float acc = 0.f;
        #pragma unroll
        for (int k = 0; k < 8; ++k) acc += Vb[(size_t)k * D];
        red[t] = acc;
    }
    for (int i = t; i < 64 * SK; i += 512) sidx[i] = idx[l0 * SK + i];
    __syncthreads();
    if (t < 64) {
        float s = 0.f;
        #pragma unroll
        for (int rr = 0; rr < 8; ++rr) s += red[t + rr * 64];
        Vp[(head * 32 + qc) * 64 + t] = s;
    }

    // ---- sampled-scores path (8-lane groups, DPP dot-reduce) ----
    int wave = t >> 6, lane = t & 63;
    int g  = lane >> 3;
    int dl = lane & 7;
    int lq = wave * 8 + g;                     // 0..63
    size_t qid = (size_t)head * L + (l0 + lq);

    const float4* Q4 = reinterpret_cast<const float4*>(Q);
    float4 q0 = Q4[qid * 16 + dl * 2 + 0];
    float4 q1 = Q4[qid * 16 + dl * 2 + 1];
    const float4* Kb4 = reinterpret_cast<const float4*>(K) + (size_t)head * L * 16;

    float mx = -INFINITY, sm = 0.f;
    #pragma unroll 4
    for (int s = 0; s < SK; ++s) {
        int kr = sidx[lq * SK + s];
        const float4* kp = Kb4 + (size_t)kr * 16 + dl * 2;
        float4 k0 = kp[0], k1 = kp[1];
        float p = q0.x * k0.x + q0.y * k0.y + q0.z * k0.z + q0.w * k0.w
                + q1.x * k1.x + q1.y * k1.y + q1.z * k1.z + q1.w * k1.w;
        p = dpp_add<0xB1>(p);
        p = dpp_add<0x4E>(p);
        p = dpp_add<0x12C>(p);
        mx = fmaxf(mx, p);
        sm += p;
    }
    if (dl == 0) M[qid] = mx - sm * (1.0f / (float)L);

    // ---- last-block-per-head handoff ----
    __threadfence();
    __syncthreads();
    __shared__ unsigned int lastflag;
    if (t == 0) lastflag = (atomicAdd(&cnt1[head], 1u) == 31u) ? 1u : 0u;
    __syncthreads();
    if (!lastflag) return;
    __threadfence();   // acquire: all 32 blocks' M/Vp stores visible

    // ======== consumer: select for `head`, 512 threads, uniform barriers ========
    __shared__ unsigned int keys[L];
    __shared__ int hist[256];
    __shared__ int ssum[256];
    __shared__ int bsel;
    __shared__ unsigned int pref_s;
    __shared__ int krem_s;
    __shared__ int cnt_gt, cnt_eq;
    __shared__ int eqlist[64];
    __shared__ int stop[NT];
    int bh = head;

    if (t < 64) {
        float s = 0.f;
        #pragma unroll
        for (int c = 0; c < 32; ++c) s += Vp[(bh * 32 + c) * 64 + t];
        Vm[bh * D + t] = s * (1.0f / (float)L);
    }
    for (int i = t; i < L; i += 512) {
        unsigned int u = __float_as_uint(M[bh * L + i]);
        keys[i] = (u & 0x80000000u) ? ~u : (u | 0x80000000u);
    }
    if (t == 0) { pref_s = 0u; krem_s = NT; cnt_gt = 0; cnt_eq = 0; }
    __syncthreads();

    #pragma unroll
    for (int shift = 24; shift >= 0; shift -= 8) {
        if (t < 256) hist[t] = 0;
        __syncthreads();
        unsigned int pref = pref_s;
        for (int i = t; i < L; i += 512) {
            unsigned int k  = keys[i];
            unsigned int hi = (shift == 24) ? 0u : (k >> (shift + 8));
            if (hi == pref) atomicAdd(&hist[(k >> shift) & 0xFF], 1);
        }
        __syncthreads();
        if (t < 256) ssum[t] = hist[t];
        __syncthreads();
        for (int st = 1; st < 256; st <<= 1) {
            int v = (t < 256 && t + st < 256) ? ssum[t + st] : 0;
            __syncthreads();
            if (t < 256) ssum[t] += v;
            __syncthreads();
        }
        if (t < 256) {
            int krem = krem_s;
            int excl = ssum[t] - hist[t];
            if (excl < krem && excl + hist[t] >= krem) bsel = t;
        }
        __syncthreads();
        if (t == 0) {
            int bb = bsel;
            krem_s = krem_s - (ssum[bb] - hist[bb]);
            pref_s = (pref_s << 8) | (unsigned int)bb;
        }
        __syncthreads();
    }

    unsigned int T = pref_s;
    int krem = krem_s;
    for (int i = t; i < L; i += 512) {
        unsigned int k = keys[i];
        if (k > T) {
            int p = atomicAdd(&cnt_gt, 1);
            Mtop[bh * NT + p] = i;
            stop[p] = i;
        } else if (k == T) {
            int p = atomicAdd(&cnt_eq, 1);
            if (p < 64) eqlist[p] = i;
        }
    }
    __syncthreads();
    if (t == 0) {
        int base = cnt_gt;
        int m = cnt_eq < 64 ? cnt_eq : 64;
        for (int q = 0; q < krem; ++q) {
            int best = 0x7fffffff, bj = -1;
            for (int j = 0; j < m; ++j) if (eqlist[j] < best) { best = eqlist[j]; bj = j; }
            Mtop[bh * NT + base + q] = best;
            stop[base + q] = best;
            if (bj >= 0) eqlist[bj] = 0x7fffffff;
        }
    }
    __syncthreads();
    const float4* Qg = reinterpret_cast<const float4*>(Q) + (size_t)bh * L * 16;
    float4* Qt = reinterpret_cast<float4*>(Qtop) + (size_t)bh * NT * 16;
    for (int i = t; i < NT * 16; i += 512)
        Qt[i] = Qg[(size_t)stop[i >> 4] * 16 + (i & 15)];
}

// =============== Kernel 2: split-K attention partials + broadcast fill +
//                 (last block/head) softmax-combine of the 16 chunks ===============
__global__ __launch_bounds__(256, 2) void kAttnPart(const float* __restrict__ Qtop,
                                                    const float* __restrict__ K,
                                                    const float* __restrict__ V,
                                                    const float* __restrict__ Vm,
                                                    const int* __restrict__ Mtop,
                                                    float* __restrict__ Opart,
                                                    float* __restrict__ mpart,
                                                    float* __restrict__ lpart,
                                                    float* __restrict__ out,
                                                    unsigned int* __restrict__ cnt2)
{
    __shared__ float4 V4[CK * 16];         // 32 KB, swizzled
    __shared__ float  S[NT * SP];          // 20.6 KB, exp(scores)
    __shared__ float  smax[NT], ssum[NT];

    int c = blockIdx.x, bh = blockIdx.y;
    int t = threadIdx.x;

    // ---- broadcast fill of this block's output slice ----
    {
        const float4* Vm4 = reinterpret_cast<const float4*>(Vm + bh * D);
        float4* outB = reinterpret_cast<float4*>(out) + ((size_t)bh * L + c * CK) * 16;
        #pragma unroll
        for (int k = 0; k < 8; ++k) { int i = t + k * 256; outB[i] = Vm4[i & 15]; }
    }

    // ---- V chunk loads (into regs; LDS write after phase A) ----
    const float4* Vg = reinterpret_cast<const float4*>(V) + ((size_t)bh * L + c * CK) * 16;
    float4 vreg[8];
    #pragma unroll
    for (int k = 0; k < 8; ++k) vreg[k] = Vg[t + k * 256];

    // ---- K rows into registers: lane owns j0 = lane, j1 = 64+lane ----
    int w    = __builtin_amdgcn_readfirstlane(t) >> 6;
    int lane = t & 63;
    const float4* Kg = reinterpret_cast<const float4*>(K) + ((size_t)bh * L + c * CK) * 16;
    float4 k0[16], k1[16];
    #pragma unroll
    for (int d4 = 0; d4 < 16; ++d4) {
        k0[d4] = Kg[(size_t)lane * 16 + d4];
        k1[d4] = Kg[(size_t)(64 + lane) * 16 + d4];
    }

    // ---- Phase A: wave w scores its 10 queries against all 128 keys ----
    const float* Qb = Qtop + ((size_t)bh * NT + w * 10) * D;
    float p0[10], p1[10];
    #pragma unroll
    for (int i = 0; i < 10; ++i) {
        const float* qrow = Qb + i * D;
        float a0 = 0.f, a1 = 0.f;
        #pragma unroll
        for (int d4 = 0; d4 < 16; ++d4) {
            float4 q4 = *reinterpret_cast<const float4*>(qrow + d4 * 4);
            a0 += q4.x * k0[d4].x + q4.y * k0[d4].y + q4.z * k0[d4].z + q4.w * k0[d4].w;
            a1 += q4.x * k1[d4].x + q4.y * k1[d4].y + q4.z * k1[d4].z + q4.w * k1[d4].w;
        }
        p0[i] = a0 * SCALE; p1[i] = a1 * SCALE;
    }

    // ---- in-register softmax per u; exp(S) -> LDS ----
    #pragma unroll
    for (int i = 0; i < 10; ++i) {
        int u = w * 10 + i;
        float m = fmaxf(p0[i], p1[i]);
        #pragma unroll
        for (int o = 1; o < 64; o <<= 1) m = fmaxf(m, __shfl_xor(m, o, 64));
        float e0 = __expf(p0[i] - m), e1 = __expf(p1[i] - m);
        float l2 = e0 + e1;
        #pragma unroll
        for (int o = 1; o < 64; o <<= 1) l2 += __shfl_xor(l2, o, 64);
        S[u * SP + lane]      = e0;
        S[u * SP + 64 + lane] = e1;
        if (lane == 0) { smax[u] = m; ssum[u] = l2; }
    }

    // ---- V -> LDS (swizzled) ----
    #pragma unroll
    for (int k = 0; k < 8; ++k) {
        int i = t + k * 256;
        int j = i >> 4, d4 = i & 15;
        V4[j * 16 + (d4 ^ (j & 15))] = vreg[k];
    }
    __syncthreads();

    // ---- Phase B: O[u][d] = sum_j P[u][j] V[j][d] ----
    {
        int a = t >> 5, r = t & 31;
        int d4 = r >> 1, jh = r & 1;
        float4 acc[5];
        #pragma unroll
        for (int ui = 0; ui < 5; ++ui) acc[ui] = make_float4(0.f, 0.f, 0.f, 0.f);
        for (int jj = 0; jj < 64; ++jj) {
            int j = jh * 64 + jj;
            float4 v4 = V4[j * 16 + (d4 ^ (j & 15))];
            #pragma unroll
            for (int ui = 0; ui < 5; ++ui) {
                float p = S[(a + 8 * ui) * SP + j];
                acc[ui].x += p * v4.x; acc[ui].y += p * v4.y;
                acc[ui].z += p * v4.z; acc[ui].w += p * v4.w;
            }
        }
        #pragma unroll
        for (int ui = 0; ui < 5; ++ui) {
            acc[ui].x = dpp_add<0xB1>(acc[ui].x);
            acc[ui].y = dpp_add<0xB1>(acc[ui].y);
            acc[ui].z = dpp_add<0xB1>(acc[ui].z);
            acc[ui].w = dpp_add<0xB1>(acc[ui].w);
        }
        if (jh == 0) {
            float4* Og = reinterpret_cast<float4*>(Opart) + ((size_t)(bh * NC + c) * NT) * 16;
            #pragma unroll
            for (int ui = 0; ui < 5; ++ui)
                Og[(a + 8 * ui) * 16 + d4] = acc[ui];
        }
    }
    if (t < NT) {
        mpart[(bh * NC + c) * NT + t] = smax[t];
        lpart[(bh * NC + c) * NT + t] = ssum[t];
    }

    // ---- last-block-per-head: combine the 16 chunk partials ----
    __threadfence();
    __syncthreads();
    __shared__ unsigned int lastf;
    if (t == 0) lastf = (atomicAdd(&cnt2[bh], 1u) == (unsigned int)(NC - 1)) ? 1u : 0u;
    __syncthreads();
    if (!lastf) return;
    __threadfence();   // acquire: all chunks' Opart/mpart/lpart visible

    int d = t & 63;
    for (int u = t >> 6; u < NT; u += 4) {
        float gm = -INFINITY, den = 0.f, o = 0.f;
        for (int cc = 0; cc < NC; ++cc) {
            int pi = (bh * NC + cc) * NT + u;
            float mv = mpart[pi], lv = lpart[pi];
            float nm = fmaxf(gm, mv);
            float r1 = __expf(gm - nm), r2 = __expf(mv - nm);
            o   = o * r1 + r2 * Opart[(size_t)pi * D + d];
            den = den * r1 + r2 * lv;
            gm  = nm;
        }
        int qrow = Mtop[bh * NT + u];
        out[((size_t)bh * L + qrow) * D + d] = o / den;
    }
}

extern "C" void kernel_launch(void* const* d_in, const int* in_sizes, int n_in,
                              void* d_out, int out_size, void* d_ws, size_t ws_size,
                              hipStream_t stream)
{
    const float* Q   = (const float*)d_in[0];
    const float* K   = (const float*)d_in[1];
    const float* V   = (const float*)d_in[2];
    const int*   idx = (const int*)d_in[3];
    float* out = (float*)d_out;

    char* ws = (char*)d_ws;
    float* M     = (float*)(ws + WS_M);
    int*   Mtop  = (int*)  (ws + WS_MTOP);
    float* Vp    = (float*)(ws + WS_VP);
    float* Vm    = (float*)(ws + WS_VM);
    float* Qtop  = (float*)(ws + WS_QTOP);
    float* Opart = (float*)(ws + WS_OPART);
    float* mpart = (float*)(ws + WS_MPART);
    float* lpart = (float*)(ws + WS_LPART);
    unsigned int* cnt = (unsigned int*)(ws + WS_CNT);   // cnt1 = cnt, cnt2 = cnt+32

    kInit    <<<1, 64, 0, stream>>>(cnt);
    kMVTop   <<<1024, 512, 0, stream>>>(Q, K, V, idx, M, Vp, Mtop, Vm, Qtop, cnt);
    kAttnPart<<<dim3(NC, BH), 256, 0, stream>>>(Qtop, K, V, Vm, Mtop,
                                                Opart, mpart, lpart, out, cnt + 32);
}

// Round 10
// 166.123 us; speedup vs baseline: 2.5373x; 2.5373x over previous
//
#include <hip/hip_runtime.h>
#include <math.h>

#define BH 32
#define L  2048
#define D  64
#define SK 40
#define NT 40
#define NC 16          // key chunks for split-K attention
#define CK 128         // keys per chunk (NC*CK == L)
#define SP 129         // padded LDS stride for S (kills 4-way bank conflict)
#define SCALE 0.125f

// ---- workspace layout (bytes) ----
#define WS_M      0                  // float[BH*L]            = 256 KB
#define WS_MTOP   262144             // int[BH*NT]             = 5 KB
#define WS_VP     267264             // float[1024*64]         = 256 KB
#define WS_VM     529408             // float[BH*D]            = 8 KB
#define WS_QTOP   537600             // float[BH*NT*D]         = 320 KB
#define WS_OPART  865280             // float[BH*NC*NT*D]      = 5.24 MB
#define WS_MPART  6108160            // float[BH*NC*NT]        = 80 KB
#define WS_LPART  6190080            // float[BH*NC*NT]        = 80 KB

// DPP add: VALU-only cross-lane. dest lane i reads src lane (i-N) mod 16 for row_ror:N.
// 0xB1 = quad_perm xor1, 0x4E = quad_perm xor2, 0x12C = row_ror:12 -> i <- i+4.
template <int CTRL>
__device__ __forceinline__ float dpp_add(float x) {
    int y = __builtin_amdgcn_update_dpp(0, __float_as_int(x), CTRL, 0xF, 0xF, true);
    return x + __int_as_float(y);
}

// =============== Kernel 1: fused sampled-scores + V-mean partials ===============
// 1024 blocks x 512 threads. 8 queries/wave (8-lane groups); DPP dot-reduce.
// Gather layout: lane dl reads K-row float4s {dl, 8+dl} so each dwordx4
// instruction covers 2 whole 64-B lines (4 line-requests/row, not 8).
__global__ __launch_bounds__(512) void kMV(const float* __restrict__ Q,
                                           const float* __restrict__ K,
                                           const float* __restrict__ V,
                                           const int* __restrict__ idx,
                                           float* __restrict__ M,
                                           float* __restrict__ Vp)
{
    __shared__ int   sidx[64 * SK];    // 10 KB
    __shared__ float red[512];

    int t    = threadIdx.x;
    int b    = blockIdx.x;
    int head = ((b >> 3) & 3) * 8 + (b & 7);   // XCD-swizzled head
    int qc   = b >> 5;                         // 0..31
    int l0   = qc * 64;

    // ---- V-mean partial for rows l0..l0+63 of this head ----
    {
        int d = t & 63, r = t >> 6;            // r = 0..7
        const float* Vb = V + ((size_t)head * L + l0 + r * 8) * D + d;
        float acc = 0.f;
        #pragma unroll
        for (int k = 0; k < 8; ++k) acc += Vb[(size_t)k * D];
        red[t] = acc;
    }
    // ---- stage index rows (contiguous) ----
    for (int i = t; i < 64 * SK; i += 512) sidx[i] = idx[l0 * SK + i];
    __syncthreads();
    if (t < 64) {
        float s = 0.f;
        #pragma unroll
        for (int rr = 0; rr < 8; ++rr) s += red[t + rr * 64];
        Vp[(head * 32 + qc) * 64 + t] = s;
    }

    // ---- sampled-scores path ----
    int wave = t >> 6, lane = t & 63;
    int g  = lane >> 3;                        // query within wave, 0..7
    int dl = lane & 7;                         // octant slot
    int lq = wave * 8 + g;                     // 0..63
    size_t qid = (size_t)head * L + (l0 + lq);

    const float4* Q4 = reinterpret_cast<const float4*>(Q);
    float4 q0 = Q4[qid * 16 + dl];             // dims 4dl..4dl+3
    float4 q1 = Q4[qid * 16 + 8 + dl];         // dims 32+4dl..32+4dl+3
    const float4* Kb4 = reinterpret_cast<const float4*>(K) + (size_t)head * L * 16;

    float mx = -INFINITY, sm = 0.f;
    #pragma unroll 4
    for (int s = 0; s < SK; ++s) {
        int kr = sidx[lq * SK + s];
        const float4* kp = Kb4 + (size_t)kr * 16;
        float4 k0 = kp[dl];                    // lines 0-1 of the row
        float4 k1 = kp[8 + dl];                // lines 2-3 of the row
        float p = q0.x * k0.x + q0.y * k0.y + q0.z * k0.z + q0.w * k0.w
                + q1.x * k1.x + q1.y * k1.y + q1.z * k1.z + q1.w * k1.w;
        p = dpp_add<0xB1>(p);                  // + lane^1
        p = dpp_add<0x4E>(p);                  // + lane^2
        p = dpp_add<0x12C>(p);                 // + lane+4 (row_ror:12), valid at dl==0
        mx = fmaxf(mx, p);
        sm += p;
    }
    if (dl == 0) M[qid] = mx - sm * (1.0f / (float)L);
}

// =============== Kernel 2: top-40 (radix select) + V-mean finalize + Q gather ===============
__global__ __launch_bounds__(256) void kTopVm(const float* __restrict__ M,
                                              const float* __restrict__ Vp,
                                              const float* __restrict__ Q,
                                              int* __restrict__ Mtop,
                                              float* __restrict__ Vm,
                                              float* __restrict__ Qtop)
{
    __shared__ unsigned int keys[L];
    __shared__ int hist[256];
    __shared__ int ssum[256];
    __shared__ int bsel;
    __shared__ unsigned int pref_s;
    __shared__ int krem_s;
    __shared__ int cnt_gt, cnt_eq;
    __shared__ int eqlist[64];
    __shared__ int stop[NT];

    int bh = blockIdx.x;
    int t  = threadIdx.x;

    if (t < 64) {
        float s = 0.f;
        #pragma unroll
        for (int c = 0; c < 32; ++c) s += Vp[(bh * 32 + c) * 64 + t];
        Vm[bh * D + t] = s * (1.0f / (float)L);
    }

    for (int i = t; i < L; i += 256) {
        unsigned int u = __float_as_uint(M[bh * L + i]);
        keys[i] = (u & 0x80000000u) ? ~u : (u | 0x80000000u);
    }
    if (t == 0) { pref_s = 0u; krem_s = NT; cnt_gt = 0; cnt_eq = 0; }
    __syncthreads();

    #pragma unroll
    for (int shift = 24; shift >= 0; shift -= 8) {
        hist[t] = 0;
        __syncthreads();
        unsigned int pref = pref_s;
        for (int i = t; i < L; i += 256) {
            unsigned int k  = keys[i];
            unsigned int hi = (shift == 24) ? 0u : (k >> (shift + 8));
            if (hi == pref) atomicAdd(&hist[(k >> shift) & 0xFF], 1);
        }
        __syncthreads();
        ssum[t] = hist[t];
        __syncthreads();
        for (int st = 1; st < 256; st <<= 1) {
            int v = (t + st < 256) ? ssum[t + st] : 0;
            __syncthreads();
            ssum[t] += v;
            __syncthreads();
        }
        int krem = krem_s;
        int excl = ssum[t] - hist[t];
        if (excl < krem && excl + hist[t] >= krem) bsel = t;
        __syncthreads();
        if (t == 0) {
            int bb = bsel;
            krem_s = krem_s - (ssum[bb] - hist[bb]);
            pref_s = (pref_s << 8) | (unsigned int)bb;
        }
        __syncthreads();
    }

    unsigned int T = pref_s;
    int krem = krem_s;
    for (int i = t; i < L; i += 256) {
        unsigned int k = keys[i];
        if (k > T) {
            int p = atomicAdd(&cnt_gt, 1);
            Mtop[bh * NT + p] = i;
            stop[p] = i;
        } else if (k == T) {
            int p = atomicAdd(&cnt_eq, 1);
            if (p < 64) eqlist[p] = i;
        }
    }
    __syncthreads();
    if (t == 0) {
        int base = cnt_gt;
        int m = cnt_eq < 64 ? cnt_eq : 64;
        for (int q = 0; q < krem; ++q) {
            int best = 0x7fffffff, bj = -1;
            for (int j = 0; j < m; ++j) if (eqlist[j] < best) { best = eqlist[j]; bj = j; }
            Mtop[bh * NT + base + q] = best;
            stop[base + q] = best;
            if (bj >= 0) eqlist[bj] = 0x7fffffff;
        }
    }
    __syncthreads();
    // gather selected Q rows into compact Qtop (read wave-uniform in kAttnPart)
    const float4* Qg = reinterpret_cast<const float4*>(Q) + (size_t)bh * L * 16;
    float4* Qt = reinterpret_cast<float4*>(Qtop) + (size_t)bh * NT * 16;
    for (int i = t; i < NT * 16; i += 256)
        Qt[i] = Qg[(size_t)stop[i >> 4] * 16 + (i & 15)];
}

// =============== Kernel 3: split-K attention partials + V_mean broadcast fill ===============
// grid (NC, BH). K rows live in registers (lane owns j=lane and j=lane+64);
// Q via wave-uniform loads; in-register softmax; only V and exp(S) round-trip
// through LDS. One barrier.
__global__ __launch_bounds__(256, 2) void kAttnPart(const float* __restrict__ Qtop,
                                                    const float* __restrict__ K,
                                                    const float* __restrict__ V,
                                                    const float* __restrict__ Vm,
                                                    float* __restrict__ Opart,
                                                    float* __restrict__ mpart,
                                                    float* __restrict__ lpart,
                                                    float* __restrict__ out)
{
    __shared__ float4 V4[CK * 16];         // 32 KB, swizzled
    __shared__ float  S[NT * SP];          // 20.6 KB, exp(scores)
    __shared__ float  smax[NT], ssum[NT];

    int c = blockIdx.x, bh = blockIdx.y;
    int t = threadIdx.x;

    // ---- broadcast fill of this block's output slice ----
    {
        const float4* Vm4 = reinterpret_cast<const float4*>(Vm + bh * D);
        float4* outB = reinterpret_cast<float4*>(out) + ((size_t)bh * L + c * CK) * 16;
        #pragma unroll
        for (int k = 0; k < 8; ++k) { int i = t + k * 256; outB[i] = Vm4[i & 15]; }
    }

    // ---- V chunk loads (coalesced, into regs; LDS write after phase A) ----
    const float4* Vg = reinterpret_cast<const float4*>(V) + ((size_t)bh * L + c * CK) * 16;
    float4 vreg[8];
    #pragma unroll
    for (int k = 0; k < 8; ++k) vreg[k] = Vg[t + k * 256];

    // ---- K rows into registers: lane owns j0 = lane, j1 = 64+lane ----
    int w    = __builtin_amdgcn_readfirstlane(t) >> 6;   // scalar wave id
    int lane = t & 63;
    const float4* Kg = reinterpret_cast<const float4*>(K) + ((size_t)bh * L + c * CK) * 16;
    float4 k0[16], k1[16];
    #pragma unroll
    for (int d4 = 0; d4 < 16; ++d4) {
        k0[d4] = Kg[(size_t)lane * 16 + d4];
        k1[d4] = Kg[(size_t)(64 + lane) * 16 + d4];
    }

    // ---- Phase A: wave w scores its 10 queries against all 128 keys ----
    const float* Qb = Qtop + ((size_t)bh * NT + w * 10) * D;   // wave-uniform
    float p0[10], p1[10];
    #pragma unroll
    for (int i = 0; i < 10; ++i) {
        const float* qrow = Qb + i * D;
        float a0 = 0.f, a1 = 0.f;
        #pragma unroll
        for (int d4 = 0; d4 < 16; ++d4) {
            float4 q4 = *reinterpret_cast<const float4*>(qrow + d4 * 4);
            a0 += q4.x * k0[d4].x + q4.y * k0[d4].y + q4.z * k0[d4].z + q4.w * k0[d4].w;
            a1 += q4.x * k1[d4].x + q4.y * k1[d4].y + q4.z * k1[d4].z + q4.w * k1[d4].w;
        }
        p0[i] = a0 * SCALE; p1[i] = a1 * SCALE;
    }

    // ---- in-register softmax per u; write exp(S) to LDS ----
    #pragma unroll
    for (int i = 0; i < 10; ++i) {
        int u = w * 10 + i;
        float m = fmaxf(p0[i], p1[i]);
        #pragma unroll
        for (int o = 1; o < 64; o <<= 1) m = fmaxf(m, __shfl_xor(m, o, 64));
        float e0 = __expf(p0[i] - m), e1 = __expf(p1[i] - m);
        float l2 = e0 + e1;
        #pragma unroll
        for (int o = 1; o < 64; o <<= 1) l2 += __shfl_xor(l2, o, 64);
        S[u * SP + lane]      = e0;
        S[u * SP + 64 + lane] = e1;
        if (lane == 0) { smax[u] = m; ssum[u] = l2; }
    }

    // ---- V -> LDS (swizzled) ----
    #pragma unroll
    for (int k = 0; k < 8; ++k) {
        int i = t + k * 256;
        int j = i >> 4, d4 = i & 15;
        V4[j * 16 + (d4 ^ (j & 15))] = vreg[k];
    }
    __syncthreads();

    // ---- Phase B: O[u][d] = sum_j P[u][j] V[j][d], register-tiled ----
    {
        int a = t >> 5, r = t & 31;
        int d4 = r >> 1, jh = r & 1;
        float4 acc[5];
        #pragma unroll
        for (int ui = 0; ui < 5; ++ui) acc[ui] = make_float4(0.f, 0.f, 0.f, 0.f);
        for (int jj = 0; jj < 64; ++jj) {
            int j = jh * 64 + jj;
            float4 v4 = V4[j * 16 + (d4 ^ (j & 15))];
            #pragma unroll
            for (int ui = 0; ui < 5; ++ui) {
                float p = S[(a + 8 * ui) * SP + j];
                acc[ui].x += p * v4.x; acc[ui].y += p * v4.y;
                acc[ui].z += p * v4.z; acc[ui].w += p * v4.w;
            }
        }
        #pragma unroll
        for (int ui = 0; ui < 5; ++ui) {       // combine jh pairs via quad_perm xor1
            acc[ui].x = dpp_add<0xB1>(acc[ui].x);
            acc[ui].y = dpp_add<0xB1>(acc[ui].y);
            acc[ui].z = dpp_add<0xB1>(acc[ui].z);
            acc[ui].w = dpp_add<0xB1>(acc[ui].w);
        }
        if (jh == 0) {
            float4* Og = reinterpret_cast<float4*>(Opart) + ((size_t)(bh * NC + c) * NT) * 16;
            #pragma unroll
            for (int ui = 0; ui < 5; ++ui)
                Og[(a + 8 * ui) * 16 + d4] = acc[ui];
        }
    }
    if (t < NT) {
        mpart[(bh * NC + c) * NT + t] = smax[t];
        lpart[(bh * NC + c) * NT + t] = ssum[t];
    }
}

// =============== Kernel 4: combine partials, overwrite selected rows ===============
__global__ __launch_bounds__(64) void kCombine(const float* __restrict__ Opart,
                                               const float* __restrict__ mpart,
                                               const float* __restrict__ lpart,
                                               const int* __restrict__ Mtop,
                                               float* __restrict__ out)
{
    int u = blockIdx.x, bh = blockIdx.y, d = threadIdx.x;
    float gm = -INFINITY, den = 0.f, o = 0.f;
    for (int c = 0; c < NC; ++c) {
        int pi = (bh * NC + c) * NT + u;
        float mv = mpart[pi], lv = lpart[pi];
        float nm = fmaxf(gm, mv);
        float r1 = __expf(gm - nm), r2 = __expf(mv - nm);
        o   = o * r1 + r2 * Opart[(size_t)pi * D + d];
        den = den * r1 + r2 * lv;
        gm  = nm;
    }
    int qrow = Mtop[bh * NT + u];
    out[((size_t)bh * L + qrow) * D + d] = o / den;
}

extern "C" void kernel_launch(void* const* d_in, const int* in_sizes, int n_in,
                              void* d_out, int out_size, void* d_ws, size_t ws_size,
                              hipStream_t stream)
{
    const float* Q   = (const float*)d_in[0];
    const float* K   = (const float*)d_in[1];
    const float* V   = (const float*)d_in[2];
    const int*   idx = (const int*)d_in[3];
    float* out = (float*)d_out;

    char* ws = (char*)d_ws;
    float* M     = (float*)(ws + WS_M);
    int*   Mtop  = (int*)  (ws + WS_MTOP);
    float* Vp    = (float*)(ws + WS_VP);
    float* Vm    = (float*)(ws + WS_VM);
    float* Qtop  = (float*)(ws + WS_QTOP);
    float* Opart = (float*)(ws + WS_OPART);
    float* mpart = (float*)(ws + WS_MPART);
    float* lpart = (float*)(ws + WS_LPART);

    kMV      <<<1024, 512, 0, stream>>>(Q, K, V, idx, M, Vp);
    kTopVm   <<<BH, 256, 0, stream>>>(M, Vp, Q, Mtop, Vm, Qtop);
    kAttnPart<<<dim3(NC, BH), 256, 0, stream>>>(Qtop, K, V, Vm, Opart, mpart, lpart, out);
    kCombine <<<dim3(NT, BH), 64, 0, stream>>>(Opart, mpart, lpart, Mtop, out);
}